// Round 1
// baseline (1576.700 us; speedup 1.0000x reference)
//
#include <hip/hip_runtime.h>
#include <math.h>

#define NN 32000
#define PP 1000
#define KK 40
#define INC 64
#define DD 32
#define EPSV 1e-5f

// ws layout (float offsets)
#define OFF_H   0          // h2 then BN'd h      [NN*32]
#define OFF_S   1024000    // s coords            [NN*3]
#define OFF_F   1120000    // feat, later t2      [NN*32]
#define OFF_A   2144000    // aggr (mean|max)     [NN*64]
#define OFF_P1  4192000    // BN1 partials        [125*64]
#define OFF_P2  4200000    // BN2 partials        [125*64]
#define OFF_ST1 4208000    // BN1 mean/istd       [64]
#define OFF_ST2 4208064    // BN2 mean/istd       [64]
// total 4208128 floats = ~16.8 MB

__device__ __forceinline__ float eluf(float v){ return v > 0.f ? v : expm1f(v); }

// deterministic per-block channel sums/sumsqs -> dst[64]
__device__ __forceinline__ void partial_stats(float (*wpart)[64], float* dst,
                                              const float* v, int tid)
{
  float s[DD], q[DD];
#pragma unroll
  for (int c = 0; c < DD; ++c){ s[c] = v[c]; q[c] = v[c]*v[c]; }
#pragma unroll
  for (int o = 32; o > 0; o >>= 1){
#pragma unroll
    for (int c = 0; c < DD; ++c){ s[c] += __shfl_xor(s[c], o); q[c] += __shfl_xor(q[c], o); }
  }
  int lane = tid & 63, wid = tid >> 6;
  if (lane == 0){
#pragma unroll
    for (int c = 0; c < DD; ++c){ wpart[wid][c] = s[c]; wpart[wid][DD+c] = q[c]; }
  }
  __syncthreads();
  if (tid < 64) dst[tid] = wpart[0][tid] + wpart[1][tid] + wpart[2][tid] + wpart[3][tid];
}

__global__ __launch_bounds__(256) void k_pre(const float* __restrict__ x,
    const float* __restrict__ w1, const float* __restrict__ b1,
    const float* __restrict__ w2, const float* __restrict__ b2,
    float* __restrict__ ws)
{
  __shared__ float lw1[INC*DD], lw2[DD*DD], lb1[DD], lb2[DD];
  __shared__ float wpart[4][64];
  int tid = threadIdx.x;
  for (int i = tid; i < INC*DD; i += 256) lw1[i] = w1[i];
  for (int i = tid; i < DD*DD; i += 256) lw2[i] = w2[i];
  if (tid < DD){ lb1[tid] = b1[tid]; lb2[tid] = b2[tid]; }
  __syncthreads();
  int node = blockIdx.x * 256 + tid;

  float acc[DD];
#pragma unroll
  for (int c = 0; c < DD; ++c) acc[c] = lb1[c];
  const float4* xr = reinterpret_cast<const float4*>(x + (size_t)node * INC);
#pragma unroll
  for (int k4 = 0; k4 < INC/4; ++k4){
    float4 xv = xr[k4];
    float xs[4] = {xv.x, xv.y, xv.z, xv.w};
#pragma unroll
    for (int u = 0; u < 4; ++u){
      int k = k4*4 + u;
#pragma unroll
      for (int c = 0; c < DD; ++c) acc[c] = fmaf(xs[u], lw1[k*DD + c], acc[c]);
    }
  }
  float h1[DD];
#pragma unroll
  for (int c = 0; c < DD; ++c) h1[c] = eluf(acc[c]);
#pragma unroll
  for (int c = 0; c < DD; ++c) acc[c] = lb2[c];
#pragma unroll
  for (int k = 0; k < DD; ++k){
    float hk = h1[k];
#pragma unroll
    for (int c = 0; c < DD; ++c) acc[c] = fmaf(hk, lw2[k*DD + c], acc[c]);
  }
  float h2[DD];
#pragma unroll
  for (int c = 0; c < DD; ++c) h2[c] = eluf(acc[c]);
  float4* hr = reinterpret_cast<float4*>(ws + OFF_H + (size_t)node * DD);
#pragma unroll
  for (int i = 0; i < DD/4; ++i)
    hr[i] = make_float4(h2[4*i], h2[4*i+1], h2[4*i+2], h2[4*i+3]);
  partial_stats(wpart, ws + OFF_P1 + blockIdx.x*64, h2, tid);
}

__global__ void k_stats(const float* __restrict__ part, float* __restrict__ stats, int nblk)
{
  __shared__ float tot[64];
  int tid = threadIdx.x;   // 64 threads
  float acc = 0.f;
  for (int b = 0; b < nblk; ++b) acc += part[b*64 + tid];
  tot[tid] = acc;
  __syncthreads();
  if (tid < 32){
    float m = tot[tid] * (1.f/NN);
    float q = tot[32+tid] * (1.f/NN);
    stats[tid] = m;
    stats[32+tid] = rsqrtf(q - m*m + EPSV);
  }
}

__global__ __launch_bounds__(256) void k_sfeat(
    const float* __restrict__ sw, const float* __restrict__ sb,
    const float* __restrict__ hw, const float* __restrict__ hb,
    const float* __restrict__ g, const float* __restrict__ b,
    float* __restrict__ ws)
{
  __shared__ float lsw[DD*3], lhw[DD*DD], lsb[4], lhb[DD], lstat[64], lg[DD], lb[DD];
  int tid = threadIdx.x;
  for (int i = tid; i < DD*3; i += 256) lsw[i] = sw[i];
  for (int i = tid; i < DD*DD; i += 256) lhw[i] = hw[i];
  if (tid < 3) lsb[tid] = sb[tid];
  if (tid < DD){ lhb[tid] = hb[tid]; lg[tid] = g[tid]; lb[tid] = b[tid]; }
  if (tid >= 64 && tid < 128) lstat[tid-64] = ws[OFF_ST1 + tid - 64];
  __syncthreads();
  int node = blockIdx.x*256 + tid;
  float hv[DD];
  float4* hr = reinterpret_cast<float4*>(ws + OFF_H + (size_t)node*DD);
#pragma unroll
  for (int i = 0; i < DD/4; ++i){ float4 v = hr[i]; hv[4*i]=v.x; hv[4*i+1]=v.y; hv[4*i+2]=v.z; hv[4*i+3]=v.w; }
#pragma unroll
  for (int c = 0; c < DD; ++c)
    hv[c] = (hv[c] - lstat[c]) * lstat[32+c] * lg[c] + lb[c];
#pragma unroll
  for (int i = 0; i < DD/4; ++i)
    hr[i] = make_float4(hv[4*i], hv[4*i+1], hv[4*i+2], hv[4*i+3]);
  float s0 = lsb[0], s1 = lsb[1], s2 = lsb[2];
#pragma unroll
  for (int k = 0; k < DD; ++k){
    s0 = fmaf(hv[k], lsw[k*3+0], s0);
    s1 = fmaf(hv[k], lsw[k*3+1], s1);
    s2 = fmaf(hv[k], lsw[k*3+2], s2);
  }
  ws[OFF_S + (size_t)node*3 + 0] = s0;
  ws[OFF_S + (size_t)node*3 + 1] = s1;
  ws[OFF_S + (size_t)node*3 + 2] = s2;
  float f[DD];
#pragma unroll
  for (int c = 0; c < DD; ++c) f[c] = lhb[c];
#pragma unroll
  for (int k = 0; k < DD; ++k){
    float hk = hv[k];
#pragma unroll
    for (int c = 0; c < DD; ++c) f[c] = fmaf(hk, lhw[k*DD+c], f[c]);
  }
  float4* fr = reinterpret_cast<float4*>(ws + OFF_F + (size_t)node*DD);
#pragma unroll
  for (int i = 0; i < DD/4; ++i)
    fr[i] = make_float4(f[4*i], f[4*i+1], f[4*i+2], f[4*i+3]);
}

// one wave per node: distances held as uint keys (16/lane), kth-smallest via
// binary search on bit space, then ballot-enumerated aggregation
__global__ __launch_bounds__(256) void k_knn(float* __restrict__ ws)
{
  const float* sp = ws + OFF_S;
  const float* fp = ws + OFF_F;
  int tid = threadIdx.x;
  int lane = tid & 63, wid = tid >> 6;
  int n = blockIdx.x * 4 + wid;     // 250 blocks per event -> same event per block
  int e = n / PP;
  int base = e * PP;
  float sx = sp[(size_t)n*3+0], sy = sp[(size_t)n*3+1], sz = sp[(size_t)n*3+2];
  unsigned keys[16];
#pragma unroll
  for (int t = 0; t < 16; ++t){
    int j = lane + 64*t;
    float d2 = __builtin_inff();
    if (j < PP){
      const float* sj = sp + (size_t)(base + j)*3;
      float dx = sj[0]-sx, dy = sj[1]-sy, dz = sj[2]-sz;
      d2 = dx*dx + dy*dy + dz*dz;
    }
    keys[t] = __float_as_uint(d2);   // nonneg floats: bits are order-monotone
  }
  unsigned lo = 0u, hi = 0x7F7FFFFFu;
  while (lo < hi){
    unsigned mid = (lo + hi) >> 1;
    int c = 0;
#pragma unroll
    for (int t = 0; t < 16; ++t) c += (keys[t] <= mid) ? 1 : 0;
#pragma unroll
    for (int o = 32; o > 0; o >>= 1) c += __shfl_xor(c, o);
    if (c >= KK) hi = mid; else lo = mid + 1;
  }
  unsigned kth = lo;
  float accm = 0.f, accx = -__builtin_inff();
  bool act = lane < DD;
#pragma unroll
  for (int t = 0; t < 16; ++t){
    unsigned long long mask = __ballot(keys[t] <= kth);
    while (mask){
      int l = __builtin_ctzll(mask);
      mask &= mask - 1;
      unsigned kb = __shfl(keys[t], l);
      int j = l + 64*t;
      float wgt = expf(-10.f * __uint_as_float(kb));
      float fv = act ? fp[(size_t)(base + j)*DD + lane] : 0.f;
      float m = wgt * fv;
      accm += m;
      accx = fmaxf(accx, m);
    }
  }
  if (act){
    ws[OFF_A + (size_t)n*64 + lane]      = accm * (1.f/KK);
    ws[OFF_A + (size_t)n*64 + DD + lane] = accx;
  }
}

__global__ __launch_bounds__(256) void k_post(
    const float* __restrict__ o1w, const float* __restrict__ o2w, const float* __restrict__ o2b,
    const float* __restrict__ p1w, const float* __restrict__ p1b,
    const float* __restrict__ p2w, const float* __restrict__ p2b,
    float* __restrict__ ws)
{
  __shared__ float l1[DD*DD], l2[2*DD*DD], lp1[67*DD], lp2[DD*DD];
  __shared__ float l2b[DD], lp1b[DD], lp2b[DD];
  __shared__ float wpart[4][64];
  int tid = threadIdx.x;
  for (int i = tid; i < DD*DD; i += 256) l1[i] = o1w[i];
  for (int i = tid; i < 2*DD*DD; i += 256) l2[i] = o2w[i];
  for (int i = tid; i < 67*DD; i += 256) lp1[i] = p1w[i];
  for (int i = tid; i < DD*DD; i += 256) lp2[i] = p2w[i];
  if (tid < DD){ l2b[tid] = o2b[tid]; lp1b[tid] = p1b[tid]; lp2b[tid] = p2b[tid]; }
  __syncthreads();
  int node = blockIdx.x*256 + tid;
  float hv[DD];
  const float4* hr = reinterpret_cast<const float4*>(ws + OFF_H + (size_t)node*DD);
#pragma unroll
  for (int i = 0; i < DD/4; ++i){ float4 v = hr[i]; hv[4*i]=v.x; hv[4*i+1]=v.y; hv[4*i+2]=v.z; hv[4*i+3]=v.w; }
  float xg[DD];
#pragma unroll
  for (int c = 0; c < DD; ++c) xg[c] = l2b[c];
#pragma unroll
  for (int k = 0; k < DD; ++k){
    float hk = hv[k];
#pragma unroll
    for (int c = 0; c < DD; ++c) xg[c] = fmaf(hk, l1[k*DD+c], xg[c]);
  }
  const float4* ar = reinterpret_cast<const float4*>(ws + OFF_A + (size_t)node*2*DD);
#pragma unroll
  for (int k4 = 0; k4 < (2*DD)/4; ++k4){
    float4 a = ar[k4];
    float as[4] = {a.x, a.y, a.z, a.w};
#pragma unroll
    for (int u = 0; u < 4; ++u){
      int k = k4*4 + u;
#pragma unroll
      for (int c = 0; c < DD; ++c) xg[c] = fmaf(as[u], l2[k*DD+c], xg[c]);
    }
  }
  float s0 = ws[OFF_S + (size_t)node*3 + 0];
  float s1 = ws[OFF_S + (size_t)node*3 + 1];
  float s2 = ws[OFF_S + (size_t)node*3 + 2];
  float t1[DD];
#pragma unroll
  for (int c = 0; c < DD; ++c) t1[c] = lp1b[c];
#pragma unroll
  for (int k = 0; k < DD; ++k){
    float v = xg[k];
#pragma unroll
    for (int c = 0; c < DD; ++c) t1[c] = fmaf(v, lp1[k*DD+c], t1[c]);
  }
#pragma unroll
  for (int c = 0; c < DD; ++c){
    t1[c] = fmaf(s0, lp1[32*DD+c], t1[c]);
    t1[c] = fmaf(s1, lp1[33*DD+c], t1[c]);
    t1[c] = fmaf(s2, lp1[34*DD+c], t1[c]);
  }
#pragma unroll
  for (int k = 0; k < DD; ++k){
    float v = hv[k];
#pragma unroll
    for (int c = 0; c < DD; ++c) t1[c] = fmaf(v, lp1[(35+k)*DD+c], t1[c]);
  }
#pragma unroll
  for (int c = 0; c < DD; ++c) t1[c] = eluf(t1[c]);
  float t2[DD];
#pragma unroll
  for (int c = 0; c < DD; ++c) t2[c] = lp2b[c];
#pragma unroll
  for (int k = 0; k < DD; ++k){
    float v = t1[k];
#pragma unroll
    for (int c = 0; c < DD; ++c) t2[c] = fmaf(v, lp2[k*DD+c], t2[c]);
  }
#pragma unroll
  for (int c = 0; c < DD; ++c) t2[c] = eluf(t2[c]);
  float4* tr = reinterpret_cast<float4*>(ws + OFF_F + (size_t)node*DD);
#pragma unroll
  for (int i = 0; i < DD/4; ++i)
    tr[i] = make_float4(t2[4*i], t2[4*i+1], t2[4*i+2], t2[4*i+3]);
  partial_stats(wpart, ws + OFF_P2 + blockIdx.x*64, t2, tid);
}

__global__ __launch_bounds__(256) void k_bnout(
    const float* __restrict__ g, const float* __restrict__ b,
    const float* __restrict__ ws, float* __restrict__ out)
{
  __shared__ float lstat[64], lg[DD], lb[DD];
  int tid = threadIdx.x;
  if (tid < 64) lstat[tid] = ws[OFF_ST2 + tid];
  if (tid >= 64 && tid < 96){ lg[tid-64] = g[tid-64]; lb[tid-64] = b[tid-64]; }
  __syncthreads();
  int node = blockIdx.x*256 + tid;
  const float4* tr = reinterpret_cast<const float4*>(ws + OFF_F + (size_t)node*DD);
  float4* orow = reinterpret_cast<float4*>(out + (size_t)node*DD);
#pragma unroll
  for (int i = 0; i < DD/4; ++i){
    float4 v = tr[i];
    float vv[4] = {v.x, v.y, v.z, v.w};
#pragma unroll
    for (int u = 0; u < 4; ++u){
      int c = 4*i + u;
      vv[u] = (vv[u] - lstat[c]) * lstat[32+c] * lg[c] + lb[c];
    }
    orow[i] = make_float4(vv[0], vv[1], vv[2], vv[3]);
  }
}

extern "C" void kernel_launch(void* const* d_in, const int* in_sizes, int n_in,
                              void* d_out, int out_size, void* d_ws, size_t ws_size,
                              hipStream_t stream)
{
  const float* x       = (const float*)d_in[0];
  // d_in[1] original_coords: unused by reference
  // d_in[2] batch: implicit (fixed B*P layout), unused
  const float* pre_w1  = (const float*)d_in[3];
  const float* pre_b1  = (const float*)d_in[4];
  const float* pre_w2  = (const float*)d_in[5];
  const float* pre_b2  = (const float*)d_in[6];
  const float* bn1_g   = (const float*)d_in[7];
  const float* bn1_b   = (const float*)d_in[8];
  const float* lin_s_w = (const float*)d_in[9];
  const float* lin_s_b = (const float*)d_in[10];
  const float* lin_h_w = (const float*)d_in[11];
  const float* lin_h_b = (const float*)d_in[12];
  const float* out1_w  = (const float*)d_in[13];
  const float* out2_w  = (const float*)d_in[14];
  const float* out2_b  = (const float*)d_in[15];
  const float* post_w1 = (const float*)d_in[16];
  const float* post_b1 = (const float*)d_in[17];
  const float* post_w2 = (const float*)d_in[18];
  const float* post_b2 = (const float*)d_in[19];
  const float* bn2_g   = (const float*)d_in[20];
  const float* bn2_b   = (const float*)d_in[21];
  float* ws  = (float*)d_ws;
  float* out = (float*)d_out;

  k_pre  <<<125, 256, 0, stream>>>(x, pre_w1, pre_b1, pre_w2, pre_b2, ws);
  k_stats<<<1, 64, 0, stream>>>(ws + OFF_P1, ws + OFF_ST1, 125);
  k_sfeat<<<125, 256, 0, stream>>>(lin_s_w, lin_s_b, lin_h_w, lin_h_b, bn1_g, bn1_b, ws);
  k_knn  <<<8000, 256, 0, stream>>>(ws);
  k_post <<<125, 256, 0, stream>>>(out1_w, out2_w, out2_b, post_w1, post_b1,
                                   post_w2, post_b2, ws);
  k_stats<<<1, 64, 0, stream>>>(ws + OFF_P2, ws + OFF_ST2, 125);
  k_bnout<<<125, 256, 0, stream>>>(bn2_g, bn2_b, ws, out);
}

// Round 3
// 601.748 us; speedup vs baseline: 2.6202x; 2.6202x over previous
//
#include <hip/hip_runtime.h>
#include <math.h>

#define NN 32000
#define PP 1000
#define KK 40
#define INC 64
#define DD 32
#define EPSV 1e-5

// ws BYTE offsets (all 8-aligned). Total ~21.4 MB.
#define OB_H64 0UL          // h2 -> BN'd h, f64 [NN][32]
#define OB_S64 8192000UL    // s coords f64 [NN][3]
#define OB_F32 8960000UL    // feat -> xgn -> t2, f32 [NN][32]
#define OB_A32 13056000UL   // aggr f32 [NN][64] (mean|max)
#define OB_P1  21248000UL   // BN1 partials f64 [125][64]
#define OB_P2  21312000UL   // BN2 partials f64 [125][64]
#define OB_ST1 21376000UL   // BN1 mean/istd f64 [64]
#define OB_ST2 21376512UL   // BN2 mean/istd f64 [64]

__device__ __forceinline__ double elud(double v){ return v > 0.0 ? v : expm1(v); }
__device__ __forceinline__ float eluf(float v){ return v > 0.f ? v : expm1f(v); }

// deterministic per-block channel sums/sumsqs (f64) -> dst[64]
// processes channels in halves of 16 to cap register pressure
__device__ __forceinline__ void pstats_f64(double (*wpart)[64], double* dst,
                                           const double* v, int tid)
{
  int lane = tid & 63, wid = tid >> 6;
#pragma unroll
  for (int half = 0; half < 2; ++half){
    double s[16], q[16];
#pragma unroll
    for (int i = 0; i < 16; ++i){ double x = v[half*16 + i]; s[i] = x; q[i] = x*x; }
#pragma unroll
    for (int o = 32; o > 0; o >>= 1){
#pragma unroll
      for (int i = 0; i < 16; ++i){ s[i] += __shfl_xor(s[i], o); q[i] += __shfl_xor(q[i], o); }
    }
    if (lane == 0){
#pragma unroll
      for (int i = 0; i < 16; ++i){
        wpart[wid][half*16 + i] = s[i];
        wpart[wid][32 + half*16 + i] = q[i];
      }
    }
  }
  __syncthreads();
  if (tid < 64) dst[tid] = wpart[0][tid] + wpart[1][tid] + wpart[2][tid] + wpart[3][tid];
}

__device__ __forceinline__ void pstats_f32in(double (*wpart)[64], double* dst,
                                             const float* v, int tid)
{
  int lane = tid & 63, wid = tid >> 6;
#pragma unroll
  for (int half = 0; half < 2; ++half){
    double s[16], q[16];
#pragma unroll
    for (int i = 0; i < 16; ++i){ double x = (double)v[half*16 + i]; s[i] = x; q[i] = x*x; }
#pragma unroll
    for (int o = 32; o > 0; o >>= 1){
#pragma unroll
      for (int i = 0; i < 16; ++i){ s[i] += __shfl_xor(s[i], o); q[i] += __shfl_xor(q[i], o); }
    }
    if (lane == 0){
#pragma unroll
      for (int i = 0; i < 16; ++i){
        wpart[wid][half*16 + i] = s[i];
        wpart[wid][32 + half*16 + i] = q[i];
      }
    }
  }
  __syncthreads();
  if (tid < 64) dst[tid] = wpart[0][tid] + wpart[1][tid] + wpart[2][tid] + wpart[3][tid];
}

// pre-MLP entirely in f64: h2 = elu(elu(x@w1+b1)@w2+b2)
__global__ __launch_bounds__(256) void k_pre(const float* __restrict__ x,
    const float* __restrict__ w1, const float* __restrict__ b1,
    const float* __restrict__ w2, const float* __restrict__ b2,
    char* __restrict__ ws)
{
  __shared__ double lw1[INC*DD];   // 16 KB
  __shared__ double lw2[DD*DD];    // 8 KB
  __shared__ double lb1[DD], lb2[DD];
  __shared__ double wpart[4][64];  // 2 KB
  int tid = threadIdx.x;
  for (int i = tid; i < INC*DD; i += 256) lw1[i] = (double)w1[i];
  for (int i = tid; i < DD*DD; i += 256) lw2[i] = (double)w2[i];
  if (tid < DD){ lb1[tid] = (double)b1[tid]; lb2[tid] = (double)b2[tid]; }
  __syncthreads();
  int node = blockIdx.x * 256 + tid;

  double acc[DD];
#pragma unroll
  for (int c = 0; c < DD; ++c) acc[c] = lb1[c];
  const float* xr = x + (size_t)node * INC;
#pragma unroll 4
  for (int k = 0; k < INC; ++k){
    double xv = (double)xr[k];
#pragma unroll
    for (int c = 0; c < DD; ++c) acc[c] = fma(xv, lw1[k*DD + c], acc[c]);
  }
  double h1[DD];
#pragma unroll
  for (int c = 0; c < DD; ++c) h1[c] = elud(acc[c]);
#pragma unroll
  for (int c = 0; c < DD; ++c) acc[c] = lb2[c];
#pragma unroll 4
  for (int k = 0; k < DD; ++k){
    double hk = h1[k];
#pragma unroll
    for (int c = 0; c < DD; ++c) acc[c] = fma(hk, lw2[k*DD + c], acc[c]);
  }
#pragma unroll
  for (int c = 0; c < DD; ++c) acc[c] = elud(acc[c]);
  double* hrow = (double*)(ws + OB_H64) + (size_t)node * DD;
#pragma unroll
  for (int c = 0; c < DD; ++c) hrow[c] = acc[c];
  pstats_f64(wpart, (double*)(ws + OB_P1) + blockIdx.x*64, acc, tid);
}

__global__ void k_stats(const double* __restrict__ part, double* __restrict__ stats, int nblk)
{
  __shared__ double tot[64];
  int tid = threadIdx.x;   // 64 threads
  double acc = 0.0;
  for (int b = 0; b < nblk; ++b) acc += part[b*64 + tid];
  tot[tid] = acc;
  __syncthreads();
  if (tid < 32){
    double m = tot[tid] / (double)NN;
    double q = tot[32+tid] / (double)NN;
    stats[tid] = m;
    stats[32+tid] = 1.0 / sqrt(q - m*m + EPSV);
  }
}

// BN1 (f64), s = hbn@lin_s (f64), feat = hbn@lin_h (f32)
__global__ __launch_bounds__(256) void k_sfeat(
    const float* __restrict__ sw, const float* __restrict__ sb,
    const float* __restrict__ hw, const float* __restrict__ hb,
    const float* __restrict__ g, const float* __restrict__ b,
    char* __restrict__ ws)
{
  __shared__ double lsw[DD*3], lsb[3], lstat[64], lg[DD], lbb[DD];
  __shared__ float lhw[DD*DD], lhb[DD];
  int tid = threadIdx.x;
  for (int i = tid; i < DD*3; i += 256) lsw[i] = (double)sw[i];
  for (int i = tid; i < DD*DD; i += 256) lhw[i] = hw[i];
  if (tid < 3) lsb[tid] = (double)sb[tid];
  if (tid < DD){ lhb[tid] = hb[tid]; lg[tid] = (double)g[tid]; lbb[tid] = (double)b[tid]; }
  if (tid >= 64 && tid < 128) lstat[tid-64] = ((const double*)(ws + OB_ST1))[tid-64];
  __syncthreads();
  int node = blockIdx.x*256 + tid;
  double* hrow = (double*)(ws + OB_H64) + (size_t)node*DD;
  double hbn[DD];
#pragma unroll
  for (int c = 0; c < DD; ++c){
    double x = hrow[c];
    hbn[c] = (x - lstat[c]) * lstat[32+c] * lg[c] + lbb[c];
  }
#pragma unroll
  for (int c = 0; c < DD; ++c) hrow[c] = hbn[c];
  double s0 = lsb[0], s1 = lsb[1], s2 = lsb[2];
#pragma unroll
  for (int k = 0; k < DD; ++k){
    s0 = fma(hbn[k], lsw[k*3+0], s0);
    s1 = fma(hbn[k], lsw[k*3+1], s1);
    s2 = fma(hbn[k], lsw[k*3+2], s2);
  }
  double* srow = (double*)(ws + OB_S64) + (size_t)node*3;
  srow[0] = s0; srow[1] = s1; srow[2] = s2;
  float hv[DD];
#pragma unroll
  for (int c = 0; c < DD; ++c) hv[c] = (float)hbn[c];
  float f[DD];
#pragma unroll
  for (int c = 0; c < DD; ++c) f[c] = lhb[c];
#pragma unroll 4
  for (int k = 0; k < DD; ++k){
    float hk = hv[k];
#pragma unroll
    for (int c = 0; c < DD; ++c) f[c] = fmaf(hk, lhw[k*DD+c], f[c]);
  }
  float* frow = (float*)(ws + OB_F32) + (size_t)node*DD;
#pragma unroll
  for (int i = 0; i < DD; ++i) frow[i] = f[i];
}

// one wave per node. d2 in f64 (np eval order). Exact top-k semantics:
// 40x extract-min with (d2, index) lexicographic tie-break.
__global__ __launch_bounds__(256) void k_knn(char* __restrict__ ws)
{
  const double* sp = (const double*)(ws + OB_S64);
  const float*  fp = (const float*)(ws + OB_F32);
  float* ap = (float*)(ws + OB_A32);
  int tid = threadIdx.x;
  int lane = tid & 63, wid = tid >> 6;
  int n = blockIdx.x * 4 + wid;
  int e = n / PP;
  int base = e * PP;
  double sx = sp[(size_t)n*3+0], sy = sp[(size_t)n*3+1], sz = sp[(size_t)n*3+2];
  double d2v[16];
#pragma unroll
  for (int t = 0; t < 16; ++t){
    int j = lane + 64*t;
    double d2 = __builtin_inf();
    if (j < PP){
      const double* sj = sp + (size_t)(base + j)*3;
      double dx = sj[0]-sx, dy = sj[1]-sy, dz = sj[2]-sz;
      d2 = (dx*dx + dy*dy) + dz*dz;   // np summation order, no fma
    }
    d2v[t] = d2;
  }
  float accm = 0.f, accx = -__builtin_inff();
  bool act = lane < DD;
  unsigned taken = 0u;
  for (int it = 0; it < KK; ++it){
    // lane-local min over not-taken slots (lowest t wins ties -> lowest j)
    double bv = __builtin_inf();
    int bs = -1;
#pragma unroll
    for (int t = 0; t < 16; ++t){
      bool ok = !((taken >> t) & 1u) && (d2v[t] < bv);
      bv = ok ? d2v[t] : bv;
      bs = ok ? t : bs;
    }
    int bj = lane + 64*bs;   // event-local index (garbage if bs<0, bv=inf loses)
    // cross-lane lexicographic min on (bv, bj)
#pragma unroll
    for (int o = 32; o > 0; o >>= 1){
      double ov = __shfl_xor(bv, o);
      int oj = __shfl_xor(bj, o);
      if (ov < bv || (ov == bv && oj < bj)){ bv = ov; bj = oj; }
    }
    float wgt = expf(-10.f * (float)bv);
    float fv = act ? fp[(size_t)(base + bj)*DD + lane] : 0.f;
    float m = wgt * fv;
    accm += m;
    accx = fmaxf(accx, m);
    if ((bj & 63) == lane) taken |= 1u << (bj >> 6);
  }
  if (act){
    ap[(size_t)n*64 + lane]      = accm * (1.f/KK);
    ap[(size_t)n*64 + DD + lane] = accx;
  }
}

// xgn = h @ out1_w + aggr @ out2_w + out2_b (f32), write over F32
__global__ __launch_bounds__(256) void k_xgn(
    const float* __restrict__ o1w, const float* __restrict__ o2w,
    const float* __restrict__ o2b, char* __restrict__ ws)
{
  __shared__ float l1[DD*DD], l2[2*DD*DD], l2b[DD];
  int tid = threadIdx.x;
  for (int i = tid; i < DD*DD; i += 256) l1[i] = o1w[i];
  for (int i = tid; i < 2*DD*DD; i += 256) l2[i] = o2w[i];
  if (tid < DD) l2b[tid] = o2b[tid];
  __syncthreads();
  int node = blockIdx.x*256 + tid;
  float xg[DD];
#pragma unroll
  for (int c = 0; c < DD; ++c) xg[c] = l2b[c];
  const double* hr = (const double*)(ws + OB_H64) + (size_t)node*DD;
#pragma unroll 4
  for (int k = 0; k < DD; ++k){
    float hk = (float)hr[k];
#pragma unroll
    for (int c = 0; c < DD; ++c) xg[c] = fmaf(hk, l1[k*DD+c], xg[c]);
  }
  const float4* ar = (const float4*)(ws + OB_A32 + (size_t)node*2*DD*4);
#pragma unroll 2
  for (int k4 = 0; k4 < (2*DD)/4; ++k4){
    float4 a = ar[k4];
    float as[4] = {a.x, a.y, a.z, a.w};
#pragma unroll
    for (int u = 0; u < 4; ++u){
      int k = k4*4 + u;
#pragma unroll
      for (int c = 0; c < DD; ++c) xg[c] = fmaf(as[u], l2[k*DD+c], xg[c]);
    }
  }
  float* frow = (float*)(ws + OB_F32) + (size_t)node*DD;
#pragma unroll
  for (int i = 0; i < DD; ++i) frow[i] = xg[i];
}

// t2 = elu(elu([xgn|s|h] @ p1w + p1b) @ p2w + p2b), write over F32, BN2 partials
__global__ __launch_bounds__(256) void k_post2(
    const float* __restrict__ p1w, const float* __restrict__ p1b,
    const float* __restrict__ p2w, const float* __restrict__ p2b,
    char* __restrict__ ws)
{
  __shared__ float lp1[67*DD], lp2[DD*DD], lp1b[DD], lp2b[DD];
  __shared__ double wpart[4][64];
  int tid = threadIdx.x;
  for (int i = tid; i < 67*DD; i += 256) lp1[i] = p1w[i];
  for (int i = tid; i < DD*DD; i += 256) lp2[i] = p2w[i];
  if (tid < DD){ lp1b[tid] = p1b[tid]; lp2b[tid] = p2b[tid]; }
  __syncthreads();
  int node = blockIdx.x*256 + tid;
  float t1[DD];
#pragma unroll
  for (int c = 0; c < DD; ++c) t1[c] = lp1b[c];
  // rows 0..31: xgn
  const float* xr = (const float*)(ws + OB_F32) + (size_t)node*DD;
#pragma unroll 4
  for (int k = 0; k < DD; ++k){
    float v = xr[k];
#pragma unroll
    for (int c = 0; c < DD; ++c) t1[c] = fmaf(v, lp1[k*DD+c], t1[c]);
  }
  // rows 32..34: s
  {
    const double* srow = (const double*)(ws + OB_S64) + (size_t)node*3;
    float s0 = (float)srow[0], s1 = (float)srow[1], s2 = (float)srow[2];
#pragma unroll
    for (int c = 0; c < DD; ++c){
      t1[c] = fmaf(s0, lp1[32*DD+c], t1[c]);
      t1[c] = fmaf(s1, lp1[33*DD+c], t1[c]);
      t1[c] = fmaf(s2, lp1[34*DD+c], t1[c]);
    }
  }
  // rows 35..66: h (x_input)
  const double* hr = (const double*)(ws + OB_H64) + (size_t)node*DD;
#pragma unroll 4
  for (int k = 0; k < DD; ++k){
    float v = (float)hr[k];
#pragma unroll
    for (int c = 0; c < DD; ++c) t1[c] = fmaf(v, lp1[(35+k)*DD+c], t1[c]);
  }
#pragma unroll
  for (int c = 0; c < DD; ++c) t1[c] = eluf(t1[c]);
  float t2[DD];
#pragma unroll
  for (int c = 0; c < DD; ++c) t2[c] = lp2b[c];
#pragma unroll 4
  for (int k = 0; k < DD; ++k){
    float v = t1[k];
#pragma unroll
    for (int c = 0; c < DD; ++c) t2[c] = fmaf(v, lp2[k*DD+c], t2[c]);
  }
#pragma unroll
  for (int c = 0; c < DD; ++c) t2[c] = eluf(t2[c]);
  float* tr = (float*)(ws + OB_F32) + (size_t)node*DD;
#pragma unroll
  for (int i = 0; i < DD; ++i) tr[i] = t2[i];
  pstats_f32in(wpart, (double*)(ws + OB_P2) + blockIdx.x*64, t2, tid);
}

__global__ __launch_bounds__(256) void k_bnout(
    const float* __restrict__ g, const float* __restrict__ b,
    const char* __restrict__ ws, float* __restrict__ out)
{
  __shared__ float lstat[64], lg[DD], lb[DD];
  int tid = threadIdx.x;
  if (tid < 64) lstat[tid] = (float)((const double*)(ws + OB_ST2))[tid];
  if (tid >= 64 && tid < 96){ lg[tid-64] = g[tid-64]; lb[tid-64] = b[tid-64]; }
  __syncthreads();
  int node = blockIdx.x*256 + tid;
  const float* tr = (const float*)(ws + OB_F32) + (size_t)node*DD;
  float* orow = out + (size_t)node*DD;
#pragma unroll
  for (int c = 0; c < DD; ++c)
    orow[c] = (tr[c] - lstat[c]) * lstat[32+c] * lg[c] + lb[c];
}

extern "C" void kernel_launch(void* const* d_in, const int* in_sizes, int n_in,
                              void* d_out, int out_size, void* d_ws, size_t ws_size,
                              hipStream_t stream)
{
  const float* x       = (const float*)d_in[0];
  const float* pre_w1  = (const float*)d_in[3];
  const float* pre_b1  = (const float*)d_in[4];
  const float* pre_w2  = (const float*)d_in[5];
  const float* pre_b2  = (const float*)d_in[6];
  const float* bn1_g   = (const float*)d_in[7];
  const float* bn1_b   = (const float*)d_in[8];
  const float* lin_s_w = (const float*)d_in[9];
  const float* lin_s_b = (const float*)d_in[10];
  const float* lin_h_w = (const float*)d_in[11];
  const float* lin_h_b = (const float*)d_in[12];
  const float* out1_w  = (const float*)d_in[13];
  const float* out2_w  = (const float*)d_in[14];
  const float* out2_b  = (const float*)d_in[15];
  const float* post_w1 = (const float*)d_in[16];
  const float* post_b1 = (const float*)d_in[17];
  const float* post_w2 = (const float*)d_in[18];
  const float* post_b2 = (const float*)d_in[19];
  const float* bn2_g   = (const float*)d_in[20];
  const float* bn2_b   = (const float*)d_in[21];
  char* ws  = (char*)d_ws;
  float* out = (float*)d_out;

  k_pre  <<<125, 256, 0, stream>>>(x, pre_w1, pre_b1, pre_w2, pre_b2, ws);
  k_stats<<<1, 64, 0, stream>>>((const double*)(ws + OB_P1), (double*)(ws + OB_ST1), 125);
  k_sfeat<<<125, 256, 0, stream>>>(lin_s_w, lin_s_b, lin_h_w, lin_h_b, bn1_g, bn1_b, ws);
  k_knn  <<<8000, 256, 0, stream>>>(ws);
  k_xgn  <<<125, 256, 0, stream>>>(out1_w, out2_w, out2_b, ws);
  k_post2<<<125, 256, 0, stream>>>(post_w1, post_b1, post_w2, post_b2, ws);
  k_stats<<<1, 64, 0, stream>>>((const double*)(ws + OB_P2), (double*)(ws + OB_ST2), 125);
  k_bnout<<<125, 256, 0, stream>>>(bn2_g, bn2_b, ws, out);
}

// Round 4
// 325.387 us; speedup vs baseline: 4.8456x; 1.8493x over previous
//
#include <hip/hip_runtime.h>
#include <math.h>

#define NN 32000
#define PP 1000
#define KK 40
#define INC 64
#define DD 32
#define EPSV 1e-5

// ws BYTE offsets (all 8-aligned). Total ~21.4 MB.
#define OB_H64 0UL          // h2 -> BN'd h, f64 [NN][32]
#define OB_S64 8192000UL    // s coords f64 [NN][3]
#define OB_F32 8960000UL    // feat -> xgn -> t2, f32 [NN][32]
#define OB_A32 13056000UL   // aggr f32 [NN][64] (mean|max)
#define OB_P1  21248000UL   // BN1 partials f64 [125][64]
#define OB_P2  21312000UL   // BN2 partials f64 [125][64]
#define OB_ST1 21376000UL   // BN1 mean/istd f64 [64]
#define OB_ST2 21376512UL   // BN2 mean/istd f64 [64]

__device__ __forceinline__ double elud(double v){ return v > 0.0 ? v : expm1(v); }
__device__ __forceinline__ float eluf(float v){ return v > 0.f ? v : expm1f(v); }

// deterministic per-block channel sums/sumsqs (f64) -> dst[64]
// processes channels in halves of 16 to cap register pressure
__device__ __forceinline__ void pstats_f64(double (*wpart)[64], double* dst,
                                           const double* v, int tid)
{
  int lane = tid & 63, wid = tid >> 6;
#pragma unroll
  for (int half = 0; half < 2; ++half){
    double s[16], q[16];
#pragma unroll
    for (int i = 0; i < 16; ++i){ double x = v[half*16 + i]; s[i] = x; q[i] = x*x; }
#pragma unroll
    for (int o = 32; o > 0; o >>= 1){
#pragma unroll
      for (int i = 0; i < 16; ++i){ s[i] += __shfl_xor(s[i], o); q[i] += __shfl_xor(q[i], o); }
    }
    if (lane == 0){
#pragma unroll
      for (int i = 0; i < 16; ++i){
        wpart[wid][half*16 + i] = s[i];
        wpart[wid][32 + half*16 + i] = q[i];
      }
    }
  }
  __syncthreads();
  if (tid < 64) dst[tid] = wpart[0][tid] + wpart[1][tid] + wpart[2][tid] + wpart[3][tid];
}

__device__ __forceinline__ void pstats_f32in(double (*wpart)[64], double* dst,
                                             const float* v, int tid)
{
  int lane = tid & 63, wid = tid >> 6;
#pragma unroll
  for (int half = 0; half < 2; ++half){
    double s[16], q[16];
#pragma unroll
    for (int i = 0; i < 16; ++i){ double x = (double)v[half*16 + i]; s[i] = x; q[i] = x*x; }
#pragma unroll
    for (int o = 32; o > 0; o >>= 1){
#pragma unroll
      for (int i = 0; i < 16; ++i){ s[i] += __shfl_xor(s[i], o); q[i] += __shfl_xor(q[i], o); }
    }
    if (lane == 0){
#pragma unroll
      for (int i = 0; i < 16; ++i){
        wpart[wid][half*16 + i] = s[i];
        wpart[wid][32 + half*16 + i] = q[i];
      }
    }
  }
  __syncthreads();
  if (tid < 64) dst[tid] = wpart[0][tid] + wpart[1][tid] + wpart[2][tid] + wpart[3][tid];
}

// pre-MLP entirely in f64: h2 = elu(elu(x@w1+b1)@w2+b2)
__global__ __launch_bounds__(256) void k_pre(const float* __restrict__ x,
    const float* __restrict__ w1, const float* __restrict__ b1,
    const float* __restrict__ w2, const float* __restrict__ b2,
    char* __restrict__ ws)
{
  __shared__ double lw1[INC*DD];   // 16 KB
  __shared__ double lw2[DD*DD];    // 8 KB
  __shared__ double lb1[DD], lb2[DD];
  __shared__ double wpart[4][64];  // 2 KB
  int tid = threadIdx.x;
  for (int i = tid; i < INC*DD; i += 256) lw1[i] = (double)w1[i];
  for (int i = tid; i < DD*DD; i += 256) lw2[i] = (double)w2[i];
  if (tid < DD){ lb1[tid] = (double)b1[tid]; lb2[tid] = (double)b2[tid]; }
  __syncthreads();
  int node = blockIdx.x * 256 + tid;

  double acc[DD];
#pragma unroll
  for (int c = 0; c < DD; ++c) acc[c] = lb1[c];
  const float* xr = x + (size_t)node * INC;
#pragma unroll 4
  for (int k = 0; k < INC; ++k){
    double xv = (double)xr[k];
#pragma unroll
    for (int c = 0; c < DD; ++c) acc[c] = fma(xv, lw1[k*DD + c], acc[c]);
  }
  double h1[DD];
#pragma unroll
  for (int c = 0; c < DD; ++c) h1[c] = elud(acc[c]);
#pragma unroll
  for (int c = 0; c < DD; ++c) acc[c] = lb2[c];
#pragma unroll 4
  for (int k = 0; k < DD; ++k){
    double hk = h1[k];
#pragma unroll
    for (int c = 0; c < DD; ++c) acc[c] = fma(hk, lw2[k*DD + c], acc[c]);
  }
#pragma unroll
  for (int c = 0; c < DD; ++c) acc[c] = elud(acc[c]);
  double* hrow = (double*)(ws + OB_H64) + (size_t)node * DD;
#pragma unroll
  for (int c = 0; c < DD; ++c) hrow[c] = acc[c];
  pstats_f64(wpart, (double*)(ws + OB_P1) + blockIdx.x*64, acc, tid);
}

__global__ void k_stats(const double* __restrict__ part, double* __restrict__ stats, int nblk)
{
  __shared__ double tot[64];
  int tid = threadIdx.x;   // 64 threads
  double acc = 0.0;
  for (int b = 0; b < nblk; ++b) acc += part[b*64 + tid];
  tot[tid] = acc;
  __syncthreads();
  if (tid < 32){
    double m = tot[tid] / (double)NN;
    double q = tot[32+tid] / (double)NN;
    stats[tid] = m;
    stats[32+tid] = 1.0 / sqrt(q - m*m + EPSV);
  }
}

// BN1 (f64), s = hbn@lin_s (f64), feat = hbn@lin_h (f32)
__global__ __launch_bounds__(256) void k_sfeat(
    const float* __restrict__ sw, const float* __restrict__ sb,
    const float* __restrict__ hw, const float* __restrict__ hb,
    const float* __restrict__ g, const float* __restrict__ b,
    char* __restrict__ ws)
{
  __shared__ double lsw[DD*3], lsb[3], lstat[64], lg[DD], lbb[DD];
  __shared__ float lhw[DD*DD], lhb[DD];
  int tid = threadIdx.x;
  for (int i = tid; i < DD*3; i += 256) lsw[i] = (double)sw[i];
  for (int i = tid; i < DD*DD; i += 256) lhw[i] = hw[i];
  if (tid < 3) lsb[tid] = (double)sb[tid];
  if (tid < DD){ lhb[tid] = hb[tid]; lg[tid] = (double)g[tid]; lbb[tid] = (double)b[tid]; }
  if (tid >= 64 && tid < 128) lstat[tid-64] = ((const double*)(ws + OB_ST1))[tid-64];
  __syncthreads();
  int node = blockIdx.x*256 + tid;
  double* hrow = (double*)(ws + OB_H64) + (size_t)node*DD;
  double hbn[DD];
#pragma unroll
  for (int c = 0; c < DD; ++c){
    double x = hrow[c];
    hbn[c] = (x - lstat[c]) * lstat[32+c] * lg[c] + lbb[c];
  }
#pragma unroll
  for (int c = 0; c < DD; ++c) hrow[c] = hbn[c];
  double s0 = lsb[0], s1 = lsb[1], s2 = lsb[2];
#pragma unroll
  for (int k = 0; k < DD; ++k){
    s0 = fma(hbn[k], lsw[k*3+0], s0);
    s1 = fma(hbn[k], lsw[k*3+1], s1);
    s2 = fma(hbn[k], lsw[k*3+2], s2);
  }
  double* srow = (double*)(ws + OB_S64) + (size_t)node*3;
  srow[0] = s0; srow[1] = s1; srow[2] = s2;
  float hv[DD];
#pragma unroll
  for (int c = 0; c < DD; ++c) hv[c] = (float)hbn[c];
  float f[DD];
#pragma unroll
  for (int c = 0; c < DD; ++c) f[c] = lhb[c];
#pragma unroll 4
  for (int k = 0; k < DD; ++k){
    float hk = hv[k];
#pragma unroll
    for (int c = 0; c < DD; ++c) f[c] = fmaf(hk, lhw[k*DD+c], f[c]);
  }
  float* frow = (float*)(ws + OB_F32) + (size_t)node*DD;
#pragma unroll
  for (int i = 0; i < DD; ++i) frow[i] = f[i];
}

// one wave per node. d2 in f64 (same values as before -> same selected set).
// Selection: 40-smallest set via binary search on u32 high words of the f64
// bit-keys (ballot+popcount counting on SALU), rare low-word tie-break stage.
// Aggregation: ballot-enumerate selected into LDS list, then fixed gather loop
// with both wave halves active (2 neighbors/iter), merged via shfl_xor(32).
__global__ __launch_bounds__(256) void k_knn(char* __restrict__ ws)
{
  const double* sp = (const double*)(ws + OB_S64);
  const float*  fp = (const float*)(ws + OB_F32);
  float* ap = (float*)(ws + OB_A32);
  __shared__ int   lds_j[4][48];
  __shared__ float lds_w[4][48];
  int tid = threadIdx.x;
  int lane = tid & 63, wid = tid >> 6;
  int n = blockIdx.x * 4 + wid;
  int e = n / PP;
  int base = e * PP;
  double sx = sp[(size_t)n*3+0], sy = sp[(size_t)n*3+1], sz = sp[(size_t)n*3+2];
  double d2v[16];
  unsigned hi32[16];
#pragma unroll
  for (int t = 0; t < 16; ++t){
    int j = lane + 64*t;
    double d2 = __builtin_inf();
    if (j < PP){
      const double* sj = sp + (size_t)(base + j)*3;
      double dx = sj[0]-sx, dy = sj[1]-sy, dz = sj[2]-sz;
      d2 = (dx*dx + dy*dy) + dz*dz;   // np summation order
    }
    d2v[t] = d2;
    hi32[t] = (unsigned)(((unsigned long long)__double_as_longlong(d2)) >> 32);
  }
  // stage 1: smallest H with count(hi32 <= H) >= KK
  unsigned lo = 0u, hi = 0x7FF00000u;
  while (lo < hi){
    unsigned mid = (lo + hi) >> 1;
    int c = 0;
#pragma unroll
    for (int t = 0; t < 16; ++t) c += __popcll(__ballot(hi32[t] <= mid));
    if (c >= KK) hi = mid; else lo = mid + 1;
  }
  unsigned H = lo;
  int cLE = 0;
#pragma unroll
  for (int t = 0; t < 16; ++t) cLE += __popcll(__ballot(hi32[t] <= H));
  bool two = (cLE > KK);
  unsigned L = 0xFFFFFFFFu;
  if (two){
    int c_lt = 0;
#pragma unroll
    for (int t = 0; t < 16; ++t) c_lt += __popcll(__ballot(hi32[t] < H));
    int r = KK - c_lt;
    unsigned lo2 = 0u, hi2 = 0xFFFFFFFFu;
    while (lo2 < hi2){
      unsigned mid = lo2 + ((hi2 - lo2) >> 1);
      int c = 0;
#pragma unroll
      for (int t = 0; t < 16; ++t){
        unsigned l32 = (unsigned)((unsigned long long)__double_as_longlong(d2v[t]));
        c += __popcll(__ballot(hi32[t] == H && l32 <= mid));
      }
      if (c >= r) hi2 = mid; else lo2 = mid + 1;
    }
    L = lo2;
  }
  // enumerate selected -> LDS list (index + weight)
  unsigned long long lml = (1ull << lane) - 1ull;
  int cnt = 0;
#pragma unroll
  for (int t = 0; t < 16; ++t){
    bool sel;
    if (two){
      unsigned l32 = (unsigned)((unsigned long long)__double_as_longlong(d2v[t]));
      sel = (hi32[t] < H) || (hi32[t] == H && l32 <= L);
    } else {
      sel = (hi32[t] <= H);
    }
    unsigned long long m = __ballot(sel);
    if (sel){
      int pos = cnt + __popcll(m & lml);
      if (pos < 48){
        lds_j[wid][pos] = base + lane + 64*t;
        lds_w[wid][pos] = expf(-10.f * (float)d2v[t]);
      }
    }
    cnt += __popcll(m);
  }
  if (cnt > 48) cnt = 48;
  // gather: halves process 2 selected neighbors per iteration
  int half = lane >> 5, ch = lane & 31;
  float accm = 0.f, accx = -__builtin_inff();
  int nit = (cnt + 1) >> 1;
  for (int it = 0; it < nit; ++it){
    int si = 2*it + half;
    if (si < cnt){
      int j = lds_j[wid][si];
      float wgt = lds_w[wid][si];
      float fv = fp[(size_t)j*DD + ch];
      float m = wgt * fv;
      accm += m;
      accx = fmaxf(accx, m);
    }
  }
  accm += __shfl_xor(accm, 32);
  accx = fmaxf(accx, __shfl_xor(accx, 32));
  if (lane < DD){
    ap[(size_t)n*64 + lane]      = accm * (1.f/KK);
    ap[(size_t)n*64 + DD + lane] = accx;
  }
}

// xgn = h @ out1_w + aggr @ out2_w + out2_b (f32), write over F32
__global__ __launch_bounds__(256) void k_xgn(
    const float* __restrict__ o1w, const float* __restrict__ o2w,
    const float* __restrict__ o2b, char* __restrict__ ws)
{
  __shared__ float l1[DD*DD], l2[2*DD*DD], l2b[DD];
  int tid = threadIdx.x;
  for (int i = tid; i < DD*DD; i += 256) l1[i] = o1w[i];
  for (int i = tid; i < 2*DD*DD; i += 256) l2[i] = o2w[i];
  if (tid < DD) l2b[tid] = o2b[tid];
  __syncthreads();
  int node = blockIdx.x*256 + tid;
  float xg[DD];
#pragma unroll
  for (int c = 0; c < DD; ++c) xg[c] = l2b[c];
  const double* hr = (const double*)(ws + OB_H64) + (size_t)node*DD;
#pragma unroll 4
  for (int k = 0; k < DD; ++k){
    float hk = (float)hr[k];
#pragma unroll
    for (int c = 0; c < DD; ++c) xg[c] = fmaf(hk, l1[k*DD+c], xg[c]);
  }
  const float4* ar = (const float4*)(ws + OB_A32 + (size_t)node*2*DD*4);
#pragma unroll 2
  for (int k4 = 0; k4 < (2*DD)/4; ++k4){
    float4 a = ar[k4];
    float as[4] = {a.x, a.y, a.z, a.w};
#pragma unroll
    for (int u = 0; u < 4; ++u){
      int k = k4*4 + u;
#pragma unroll
      for (int c = 0; c < DD; ++c) xg[c] = fmaf(as[u], l2[k*DD+c], xg[c]);
    }
  }
  float* frow = (float*)(ws + OB_F32) + (size_t)node*DD;
#pragma unroll
  for (int i = 0; i < DD; ++i) frow[i] = xg[i];
}

// t2 = elu(elu([xgn|s|h] @ p1w + p1b) @ p2w + p2b), write over F32, BN2 partials
__global__ __launch_bounds__(256) void k_post2(
    const float* __restrict__ p1w, const float* __restrict__ p1b,
    const float* __restrict__ p2w, const float* __restrict__ p2b,
    char* __restrict__ ws)
{
  __shared__ float lp1[67*DD], lp2[DD*DD], lp1b[DD], lp2b[DD];
  __shared__ double wpart[4][64];
  int tid = threadIdx.x;
  for (int i = tid; i < 67*DD; i += 256) lp1[i] = p1w[i];
  for (int i = tid; i < DD*DD; i += 256) lp2[i] = p2w[i];
  if (tid < DD){ lp1b[tid] = p1b[tid]; lp2b[tid] = p2b[tid]; }
  __syncthreads();
  int node = blockIdx.x*256 + tid;
  float t1[DD];
#pragma unroll
  for (int c = 0; c < DD; ++c) t1[c] = lp1b[c];
  // rows 0..31: xgn
  const float* xr = (const float*)(ws + OB_F32) + (size_t)node*DD;
#pragma unroll 4
  for (int k = 0; k < DD; ++k){
    float v = xr[k];
#pragma unroll
    for (int c = 0; c < DD; ++c) t1[c] = fmaf(v, lp1[k*DD+c], t1[c]);
  }
  // rows 32..34: s
  {
    const double* srow = (const double*)(ws + OB_S64) + (size_t)node*3;
    float s0 = (float)srow[0], s1 = (float)srow[1], s2 = (float)srow[2];
#pragma unroll
    for (int c = 0; c < DD; ++c){
      t1[c] = fmaf(s0, lp1[32*DD+c], t1[c]);
      t1[c] = fmaf(s1, lp1[33*DD+c], t1[c]);
      t1[c] = fmaf(s2, lp1[34*DD+c], t1[c]);
    }
  }
  // rows 35..66: h (x_input)
  const double* hr = (const double*)(ws + OB_H64) + (size_t)node*DD;
#pragma unroll 4
  for (int k = 0; k < DD; ++k){
    float v = (float)hr[k];
#pragma unroll
    for (int c = 0; c < DD; ++c) t1[c] = fmaf(v, lp1[(35+k)*DD+c], t1[c]);
  }
#pragma unroll
  for (int c = 0; c < DD; ++c) t1[c] = eluf(t1[c]);
  float t2[DD];
#pragma unroll
  for (int c = 0; c < DD; ++c) t2[c] = lp2b[c];
#pragma unroll 4
  for (int k = 0; k < DD; ++k){
    float v = t1[k];
#pragma unroll
    for (int c = 0; c < DD; ++c) t2[c] = fmaf(v, lp2[k*DD+c], t2[c]);
  }
#pragma unroll
  for (int c = 0; c < DD; ++c) t2[c] = eluf(t2[c]);
  float* tr = (float*)(ws + OB_F32) + (size_t)node*DD;
#pragma unroll
  for (int i = 0; i < DD; ++i) tr[i] = t2[i];
  pstats_f32in(wpart, (double*)(ws + OB_P2) + blockIdx.x*64, t2, tid);
}

__global__ __launch_bounds__(256) void k_bnout(
    const float* __restrict__ g, const float* __restrict__ b,
    const char* __restrict__ ws, float* __restrict__ out)
{
  __shared__ float lstat[64], lg[DD], lb[DD];
  int tid = threadIdx.x;
  if (tid < 64) lstat[tid] = (float)((const double*)(ws + OB_ST2))[tid];
  if (tid >= 64 && tid < 96){ lg[tid-64] = g[tid-64]; lb[tid-64] = b[tid-64]; }
  __syncthreads();
  int node = blockIdx.x*256 + tid;
  const float* tr = (const float*)(ws + OB_F32) + (size_t)node*DD;
  float* orow = out + (size_t)node*DD;
#pragma unroll
  for (int c = 0; c < DD; ++c)
    orow[c] = (tr[c] - lstat[c]) * lstat[32+c] * lg[c] + lb[c];
}

extern "C" void kernel_launch(void* const* d_in, const int* in_sizes, int n_in,
                              void* d_out, int out_size, void* d_ws, size_t ws_size,
                              hipStream_t stream)
{
  const float* x       = (const float*)d_in[0];
  const float* pre_w1  = (const float*)d_in[3];
  const float* pre_b1  = (const float*)d_in[4];
  const float* pre_w2  = (const float*)d_in[5];
  const float* pre_b2  = (const float*)d_in[6];
  const float* bn1_g   = (const float*)d_in[7];
  const float* bn1_b   = (const float*)d_in[8];
  const float* lin_s_w = (const float*)d_in[9];
  const float* lin_s_b = (const float*)d_in[10];
  const float* lin_h_w = (const float*)d_in[11];
  const float* lin_h_b = (const float*)d_in[12];
  const float* out1_w  = (const float*)d_in[13];
  const float* out2_w  = (const float*)d_in[14];
  const float* out2_b  = (const float*)d_in[15];
  const float* post_w1 = (const float*)d_in[16];
  const float* post_b1 = (const float*)d_in[17];
  const float* post_w2 = (const float*)d_in[18];
  const float* post_b2 = (const float*)d_in[19];
  const float* bn2_g   = (const float*)d_in[20];
  const float* bn2_b   = (const float*)d_in[21];
  char* ws  = (char*)d_ws;
  float* out = (float*)d_out;

  k_pre  <<<125, 256, 0, stream>>>(x, pre_w1, pre_b1, pre_w2, pre_b2, ws);
  k_stats<<<1, 64, 0, stream>>>((const double*)(ws + OB_P1), (double*)(ws + OB_ST1), 125);
  k_sfeat<<<125, 256, 0, stream>>>(lin_s_w, lin_s_b, lin_h_w, lin_h_b, bn1_g, bn1_b, ws);
  k_knn  <<<8000, 256, 0, stream>>>(ws);
  k_xgn  <<<125, 256, 0, stream>>>(out1_w, out2_w, out2_b, ws);
  k_post2<<<125, 256, 0, stream>>>(post_w1, post_b1, post_w2, post_b2, ws);
  k_stats<<<1, 64, 0, stream>>>((const double*)(ws + OB_P2), (double*)(ws + OB_ST2), 125);
  k_bnout<<<125, 256, 0, stream>>>(bn2_g, bn2_b, ws, out);
}